// Round 5
// baseline (268.815 us; speedup 1.0000x reference)
//
#include <hip/hip_runtime.h>

#define BATCH 131072
#define SC 2.885390081777927f   // 2*log2(e), folded into W1',b1',W2',b2'

typedef _Float16 half4 __attribute__((ext_vector_type(4)));
typedef float floatx4 __attribute__((ext_vector_type(4)));

__device__ __forceinline__ half4 u2h(uint2 u) { return __builtin_bit_cast(half4, u); }

struct hpair { half4 h, a; };

__device__ __forceinline__ hpair tanh_frag(floatx4 acc) {
    hpair P;
    #pragma unroll
    for (int r = 0; r < 4; ++r) {
        const float e = __builtin_amdgcn_exp2f(acc[r]);   // pre-scaled by 2*log2e
        const float rr = __builtin_amdgcn_rcpf(e + 1.0f);
        const float h = __builtin_fmaf(-2.0f, rr, 1.0f);
        P.h[r] = (_Float16)h;
        P.a[r] = (_Float16)__builtin_fmaf(-h, h, 1.0f);
    }
    return P;
}

// ws layout (_Float16 elements):
// [0,18432)      W2a: A-frag pairs of W2'^T incl bias row. idx=((ntp*9+kb)*64+lane)*8+half*4+j
// [18432,34816)  Ga : A-frag pairs of G, G[h][g]=W2[h][g]*C[g][h], C=W3@W1[:8,:]
// [34816,36864)  W1a: A-frags of W1'^T (K=16: 9 real + bias row k=9)
// [36864,39168)  W3a: A-frags of W3^T (N pad 16, K=144 incl bias row)

__global__ void prep_kernel(const float* __restrict__ W1, const float* __restrict__ b1,
                            const float* __restrict__ W2, const float* __restrict__ b2,
                            const float* __restrict__ W3, const float* __restrict__ b3,
                            _Float16* __restrict__ ws) {
    int idx = blockIdx.x * 256 + threadIdx.x;
    if (idx < 18432) {
        int j = idx & 3, hf = (idx >> 2) & 1, lane = (idx >> 3) & 63;
        int rem = idx >> 9, kb = rem % 9, ntp = rem / 9;
        int m = (2 * ntp + hf) * 16 + (lane & 15);
        int k = kb * 16 + (lane >> 4) * 4 + j;
        float v = (k < 128) ? SC * W2[k * 128 + m] : ((k == 128) ? SC * b2[m] : 0.0f);
        ws[idx] = (_Float16)v;
    } else if (idx < 34816) {
        int e = idx - 18432;
        int j = e & 3, hf = (e >> 2) & 1, lane = (e >> 3) & 63;
        int rem = e >> 9, kb = rem & 7, ntp = rem >> 3;
        int h = (2 * ntp + hf) * 16 + (lane & 15);
        int g = kb * 16 + (lane >> 4) * 4 + j;
        float c = 0.0f;
        #pragma unroll
        for (int d = 0; d < 8; ++d) c += W3[g * 8 + d] * W1[d * 128 + h];
        ws[idx] = (_Float16)(W2[h * 128 + g] * c);
    } else if (idx < 36864) {
        int e = idx - 34816;
        int j = e & 3, lane = (e >> 2) & 63, nt = e >> 8;
        int h = nt * 16 + (lane & 15);
        int k = (lane >> 4) * 4 + j;
        float v = (k < 9) ? SC * W1[k * 128 + h] : ((k == 9) ? SC * b1[h] : 0.0f);
        ws[idx] = (_Float16)v;
    } else if (idx < 39168) {
        int e = idx - 36864;
        int j = e & 3, lane = (e >> 2) & 63, kb = e >> 8;
        int m = lane & 15, k = kb * 16 + (lane >> 4) * 4 + j;
        float v = 0.0f;
        if (m < 8) v = (k < 128) ? W3[k * 8 + m] : ((k == 128) ? b3[m] : 0.0f);
        ws[idx] = (_Float16)v;
    }
}

__global__ __launch_bounds__(256, 4) void cnf_main(
        const float* __restrict__ z, const float* __restrict__ t_ptr,
        const _Float16* __restrict__ ws, float* __restrict__ out) {
    __shared__ unsigned short sW2[18432];   // 36,864 B: W2a A-frag pairs

    const int tid = threadIdx.x;
    {   // stage W2a: 2304 uint4
        const uint4* src = (const uint4*)ws;
        uint4* dst = (uint4*)sW2;
        #pragma unroll
        for (int i = 0; i < 9; ++i) dst[tid + i * 256] = src[tid + i * 256];
    }
    __syncthreads();

    const int lane = tid & 63;
    const int w = tid >> 6;
    const int p = lane & 15;     // sample within tile (B col / CD col)
    const int q = lane >> 4;     // quad

    half4 e1 = {(_Float16)0.0f, (_Float16)0.0f, (_Float16)0.0f, (_Float16)0.0f};
    if (q == 0) e1[0] = (_Float16)1.0f;
    const float tval = t_ptr[0];
    const uint4* sW2v = (const uint4*)sW2;
    const uint4* gav  = (const uint4*)(ws + 18432);
    const uint2* w1a  = (const uint2*)(ws + 34816);
    const uint2* w3a  = (const uint2*)(ws + 36864);

#define MFMA16(A, B, C) __builtin_amdgcn_mfma_f32_16x16x16f16((A), (B), (C), 0, 0, 0)

#define GEMM0_STEP(nt) { \
        floatx4 a0 = {0.f, 0.f, 0.f, 0.f}; \
        a0 = MFMA16(u2h(w1a[nt * 64 + lane]), xb, a0); \
        hpair P = tanh_frag(a0); h1f##nt = P.h; a1f##nt = P.a; }

#define G1KB(ntp, kb, bf) { \
        const uint4 af = sW2v[((ntp) * 9 + (kb)) * 64 + lane]; \
        ac0 = MFMA16(u2h((uint2){af.x, af.y}), bf, ac0); \
        ac1 = MFMA16(u2h((uint2){af.z, af.w}), bf, ac1); }

#define GEMM1_NTP(ntp, H0, A0, H1, A1) { \
        floatx4 ac0 = {0.f, 0.f, 0.f, 0.f}, ac1 = {0.f, 0.f, 0.f, 0.f}; \
        G1KB(ntp, 0, h1f0) G1KB(ntp, 1, h1f1) G1KB(ntp, 2, h1f2) G1KB(ntp, 3, h1f3) \
        G1KB(ntp, 4, h1f4) G1KB(ntp, 5, h1f5) G1KB(ntp, 6, h1f6) G1KB(ntp, 7, h1f7) \
        G1KB(ntp, 8, e1) \
        hpair P0 = tanh_frag(ac0); H0 = P0.h; A0 = P0.a; \
        hpair P1 = tanh_frag(ac1); H1 = P1.h; A1 = P1.a; }

#define G3(kb, bf) acc3 = MFMA16(u2h(w3a[(kb) * 64 + lane]), bf, acc3);

#define G2KB(ntp, kb, bf) { \
        const uint4 gf = gav[((ntp) * 8 + (kb)) * 64 + lane]; \
        u0 = MFMA16(u2h((uint2){gf.x, gf.y}), bf, u0); \
        u1 = MFMA16(u2h((uint2){gf.z, gf.w}), bf, u1); }

#define GEMM2_NTP(ntp, A1a, A1b) { \
        floatx4 u0 = {0.f, 0.f, 0.f, 0.f}, u1 = {0.f, 0.f, 0.f, 0.f}; \
        G2KB(ntp, 0, a2f0) G2KB(ntp, 1, a2f1) G2KB(ntp, 2, a2f2) G2KB(ntp, 3, a2f3) \
        G2KB(ntp, 4, a2f4) G2KB(ntp, 5, a2f5) G2KB(ntp, 6, a2f6) G2KB(ntp, 7, a2f7) \
        tr = __builtin_fmaf((float)A1a[0], u0[0], tr); \
        tr = __builtin_fmaf((float)A1a[1], u0[1], tr); \
        tr = __builtin_fmaf((float)A1a[2], u0[2], tr); \
        tr = __builtin_fmaf((float)A1a[3], u0[3], tr); \
        tr = __builtin_fmaf((float)A1b[0], u1[0], tr); \
        tr = __builtin_fmaf((float)A1b[1], u1[1], tr); \
        tr = __builtin_fmaf((float)A1b[2], u1[2], tr); \
        tr = __builtin_fmaf((float)A1b[3], u1[3], tr); }

    #pragma unroll 1
    for (int it = 0; it < 2; ++it) {
        const int s0 = blockIdx.x * 128 + w * 32 + it * 16;

        // ---- B-frag of X^T: B[k][n=sample]; k=q*4+j; rows 0-7=z, 8=t, 9=1(bias)
        const float4 zv = *(const float4*)(z + (size_t)(s0 + p) * 8 + (q & 1) * 4);
        half4 xb;
        if (q < 2) {
            xb[0] = (_Float16)zv.x; xb[1] = (_Float16)zv.y;
            xb[2] = (_Float16)zv.z; xb[3] = (_Float16)zv.w;
        } else if (q == 2) {
            xb[0] = (_Float16)tval; xb[1] = (_Float16)1.0f;
            xb[2] = (_Float16)0.0f; xb[3] = (_Float16)0.0f;
        } else {
            xb[0] = (_Float16)0.0f; xb[1] = (_Float16)0.0f;
            xb[2] = (_Float16)0.0f; xb[3] = (_Float16)0.0f;
        }

        // ---- GEMM0: H1^T = W1'^T @ X^T; tanh -> named h1/a1 frags
        half4 h1f0, h1f1, h1f2, h1f3, h1f4, h1f5, h1f6, h1f7;
        half4 a1f0, a1f1, a1f2, a1f3, a1f4, a1f5, a1f6, a1f7;
        GEMM0_STEP(0) GEMM0_STEP(1) GEMM0_STEP(2) GEMM0_STEP(3)
        GEMM0_STEP(4) GEMM0_STEP(5) GEMM0_STEP(6) GEMM0_STEP(7)

        // ---- GEMM1: H2pre^T = W2'^T @ H1^T (+bias row); tanh -> h2/a2 frags
        half4 h2f0, h2f1, h2f2, h2f3, h2f4, h2f5, h2f6, h2f7;
        half4 a2f0, a2f1, a2f2, a2f3, a2f4, a2f5, a2f6, a2f7;
        GEMM1_NTP(0, h2f0, a2f0, h2f1, a2f1)
        GEMM1_NTP(1, h2f2, a2f2, h2f3, a2f3)
        GEMM1_NTP(2, h2f4, a2f4, h2f5, a2f5)
        GEMM1_NTP(3, h2f6, a2f6, h2f7, a2f7)

        // ---- GEMM3: dz^T = W3^T @ H2^T (+bias row); rows = output dim d
        floatx4 acc3 = {0.f, 0.f, 0.f, 0.f};
        G3(0, h2f0) G3(1, h2f1) G3(2, h2f2) G3(3, h2f3)
        G3(4, h2f4) G3(5, h2f5) G3(6, h2f6) G3(7, h2f7) G3(8, e1)
        if (q < 2) {   // d = q*4+r in [0,8): one float4 store per lane
            float4 o; o.x = acc3[0]; o.y = acc3[1]; o.z = acc3[2]; o.w = acc3[3];
            *(float4*)(out + (size_t)(s0 + p) * 8 + q * 4) = o;
        }

        // ---- GEMM2: U^T = G @ A2^T, folded into trace immediately
        float tr = 0.0f;
        GEMM2_NTP(0, a1f0, a1f1)
        GEMM2_NTP(1, a1f2, a1f3)
        GEMM2_NTP(2, a1f4, a1f5)
        GEMM2_NTP(3, a1f6, a1f7)

        // ---- trace reduce across quads (rows of U^T), write -trace
        tr += __shfl_xor(tr, 16, 64);
        tr += __shfl_xor(tr, 32, 64);
        if (q == 0) out[(size_t)BATCH * 8 + s0 + p] = -tr;
    }
}

extern "C" void kernel_launch(void* const* d_in, const int* in_sizes, int n_in,
                              void* d_out, int out_size, void* d_ws, size_t ws_size,
                              hipStream_t stream) {
    const float* z  = (const float*)d_in[0];
    // d_in[1] = logp_z (unused by the reference math)
    const float* t  = (const float*)d_in[2];
    const float* W1 = (const float*)d_in[3];
    const float* b1 = (const float*)d_in[4];
    const float* W2 = (const float*)d_in[5];
    const float* b2 = (const float*)d_in[6];
    const float* W3 = (const float*)d_in[7];
    const float* b3 = (const float*)d_in[8];
    _Float16* ws = (_Float16*)d_ws;
    float* out = (float*)d_out;

    prep_kernel<<<153, 256, 0, stream>>>(W1, b1, W2, b2, W3, b3, ws);
    cnf_main<<<1024, 256, 0, stream>>>(z, t, ws, out);
}

// Round 6
// 159.718 us; speedup vs baseline: 1.6831x; 1.6831x over previous
//
#include <hip/hip_runtime.h>

#define BATCH 131072
#define SC 2.885390081777927f   // 2*log2(e), folded into W1',b1',W2',b2'

typedef _Float16 half4 __attribute__((ext_vector_type(4)));
typedef float floatx4 __attribute__((ext_vector_type(4)));

__device__ __forceinline__ half4 u2h(uint2 u) { return __builtin_bit_cast(half4, u); }

struct hpair { half4 h, a; };

__device__ __forceinline__ hpair tanh_frag(floatx4 acc) {
    hpair P;
    #pragma unroll
    for (int r = 0; r < 4; ++r) {
        const float e = __builtin_amdgcn_exp2f(acc[r]);   // pre-scaled by 2*log2e
        const float rr = __builtin_amdgcn_rcpf(e + 1.0f);
        const float h = __builtin_fmaf(-2.0f, rr, 1.0f);
        P.h[r] = (_Float16)h;
        P.a[r] = (_Float16)__builtin_fmaf(-h, h, 1.0f);
    }
    return P;
}

#define FENCE() __builtin_amdgcn_sched_barrier(0)

// ws layout (_Float16 elements):
// [0,18432)      W2a: A-frag pairs of W2'^T incl bias row. idx=((ntp*9+kb)*64+lane)*8+half*4+j
// [18432,34816)  Ga : A-frag pairs of G, G[h][g]=W2[h][g]*C[g][h], C=W3@W1[:8,:]
// [34816,36864)  W1a: A-frags of W1'^T (K=16: 9 real + bias row k=9)
// [36864,39168)  W3a: A-frags of W3^T (N pad 16, K=144 incl bias row)

__global__ void prep_kernel(const float* __restrict__ W1, const float* __restrict__ b1,
                            const float* __restrict__ W2, const float* __restrict__ b2,
                            const float* __restrict__ W3, const float* __restrict__ b3,
                            _Float16* __restrict__ ws) {
    int idx = blockIdx.x * 256 + threadIdx.x;
    if (idx < 18432) {
        int j = idx & 3, hf = (idx >> 2) & 1, lane = (idx >> 3) & 63;
        int rem = idx >> 9, kb = rem % 9, ntp = rem / 9;
        int m = (2 * ntp + hf) * 16 + (lane & 15);
        int k = kb * 16 + (lane >> 4) * 4 + j;
        float v = (k < 128) ? SC * W2[k * 128 + m] : ((k == 128) ? SC * b2[m] : 0.0f);
        ws[idx] = (_Float16)v;
    } else if (idx < 34816) {
        int e = idx - 18432;
        int j = e & 3, hf = (e >> 2) & 1, lane = (e >> 3) & 63;
        int rem = e >> 9, kb = rem & 7, ntp = rem >> 3;
        int h = (2 * ntp + hf) * 16 + (lane & 15);
        int g = kb * 16 + (lane >> 4) * 4 + j;
        float c = 0.0f;
        #pragma unroll
        for (int d = 0; d < 8; ++d) c += W3[g * 8 + d] * W1[d * 128 + h];
        ws[idx] = (_Float16)(W2[h * 128 + g] * c);
    } else if (idx < 36864) {
        int e = idx - 34816;
        int j = e & 3, lane = (e >> 2) & 63, nt = e >> 8;
        int h = nt * 16 + (lane & 15);
        int k = (lane >> 4) * 4 + j;
        float v = (k < 9) ? SC * W1[k * 128 + h] : ((k == 9) ? SC * b1[h] : 0.0f);
        ws[idx] = (_Float16)v;
    } else if (idx < 39168) {
        int e = idx - 36864;
        int j = e & 3, lane = (e >> 2) & 63, kb = e >> 8;
        int m = lane & 15, k = kb * 16 + (lane >> 4) * 4 + j;
        float v = 0.0f;
        if (m < 8) v = (k < 128) ? W3[k * 8 + m] : ((k == 128) ? b3[m] : 0.0f);
        ws[idx] = (_Float16)v;
    }
}

__global__ __launch_bounds__(256, 4) void cnf_main(
        const float* __restrict__ z, const float* __restrict__ t_ptr,
        const _Float16* __restrict__ ws, float* __restrict__ out) {
    __shared__ unsigned short sW2[18432];   // 36,864 B: W2a A-frag pairs

    const int tid = threadIdx.x;
    {   // stage W2a: 2304 uint4
        const uint4* src = (const uint4*)ws;
        uint4* dst = (uint4*)sW2;
        #pragma unroll
        for (int i = 0; i < 9; ++i) dst[tid + i * 256] = src[tid + i * 256];
    }
    __syncthreads();

    const int lane = tid & 63;
    const int w = tid >> 6;
    const int p = lane & 15;     // sample within tile (B col / CD col)
    const int q = lane >> 4;     // quad

    half4 e1 = {(_Float16)0.0f, (_Float16)0.0f, (_Float16)0.0f, (_Float16)0.0f};
    if (q == 0) e1[0] = (_Float16)1.0f;
    const float tval = t_ptr[0];
    const uint4* sW2v = (const uint4*)sW2;
    const uint4* gav  = (const uint4*)(ws + 18432);
    const uint2* w1a  = (const uint2*)(ws + 34816);
    const uint2* w3a  = (const uint2*)(ws + 36864);

#define MFMA16(A, B, C) __builtin_amdgcn_mfma_f32_16x16x16f16((A), (B), (C), 0, 0, 0)

#define GEMM0_STEP(nt) { \
        floatx4 a0 = {0.f, 0.f, 0.f, 0.f}; \
        a0 = MFMA16(u2h(w1a[nt * 64 + lane]), xb, a0); \
        hpair P = tanh_frag(a0); h1f##nt = P.h; a1f##nt = P.a; } \
        FENCE();

#define G1KB(ntp, kb, bf) { \
        const uint4 af = sW2v[((ntp) * 9 + (kb)) * 64 + lane]; \
        ac0 = MFMA16(u2h((uint2){af.x, af.y}), bf, ac0); \
        ac1 = MFMA16(u2h((uint2){af.z, af.w}), bf, ac1); }

#define GEMM1_NTP(ntp, H0, A0, H1, A1) { \
        floatx4 ac0 = {0.f, 0.f, 0.f, 0.f}, ac1 = {0.f, 0.f, 0.f, 0.f}; \
        G1KB(ntp, 0, h1f0) G1KB(ntp, 1, h1f1) G1KB(ntp, 2, h1f2) G1KB(ntp, 3, h1f3) \
        FENCE(); \
        G1KB(ntp, 4, h1f4) G1KB(ntp, 5, h1f5) G1KB(ntp, 6, h1f6) G1KB(ntp, 7, h1f7) \
        G1KB(ntp, 8, e1) \
        hpair P0 = tanh_frag(ac0); H0 = P0.h; A0 = P0.a; \
        hpair P1 = tanh_frag(ac1); H1 = P1.h; A1 = P1.a; } \
        FENCE();

#define G3(kb, bf) acc3 = MFMA16(u2h(w3a[(kb) * 64 + lane]), bf, acc3);

#define G2KB(ntp, kb, bf) { \
        const uint4 gf = gav[((ntp) * 8 + (kb)) * 64 + lane]; \
        u0 = MFMA16(u2h((uint2){gf.x, gf.y}), bf, u0); \
        u1 = MFMA16(u2h((uint2){gf.z, gf.w}), bf, u1); }

#define GEMM2_NTP(ntp, A1a, A1b) { \
        floatx4 u0 = {0.f, 0.f, 0.f, 0.f}, u1 = {0.f, 0.f, 0.f, 0.f}; \
        G2KB(ntp, 0, a2f0) G2KB(ntp, 1, a2f1) G2KB(ntp, 2, a2f2) G2KB(ntp, 3, a2f3) \
        FENCE(); \
        G2KB(ntp, 4, a2f4) G2KB(ntp, 5, a2f5) G2KB(ntp, 6, a2f6) G2KB(ntp, 7, a2f7) \
        tr = __builtin_fmaf((float)A1a[0], u0[0], tr); \
        tr = __builtin_fmaf((float)A1a[1], u0[1], tr); \
        tr = __builtin_fmaf((float)A1a[2], u0[2], tr); \
        tr = __builtin_fmaf((float)A1a[3], u0[3], tr); \
        tr = __builtin_fmaf((float)A1b[0], u1[0], tr); \
        tr = __builtin_fmaf((float)A1b[1], u1[1], tr); \
        tr = __builtin_fmaf((float)A1b[2], u1[2], tr); \
        tr = __builtin_fmaf((float)A1b[3], u1[3], tr); } \
        FENCE();

    #pragma unroll 1
    for (int it = 0; it < 2; ++it) {
        const int s0 = blockIdx.x * 128 + w * 32 + it * 16;

        // ---- B-frag of X^T: B[k][n=sample]; k=q*4+j; rows 0-7=z, 8=t, 9=1(bias)
        const float4 zv = *(const float4*)(z + (size_t)(s0 + p) * 8 + (q & 1) * 4);
        half4 xb;
        if (q < 2) {
            xb[0] = (_Float16)zv.x; xb[1] = (_Float16)zv.y;
            xb[2] = (_Float16)zv.z; xb[3] = (_Float16)zv.w;
        } else if (q == 2) {
            xb[0] = (_Float16)tval; xb[1] = (_Float16)1.0f;
            xb[2] = (_Float16)0.0f; xb[3] = (_Float16)0.0f;
        } else {
            xb[0] = (_Float16)0.0f; xb[1] = (_Float16)0.0f;
            xb[2] = (_Float16)0.0f; xb[3] = (_Float16)0.0f;
        }
        FENCE();

        // ---- GEMM0: H1^T = W1'^T @ X^T; tanh -> named h1/a1 frags
        half4 h1f0, h1f1, h1f2, h1f3, h1f4, h1f5, h1f6, h1f7;
        half4 a1f0, a1f1, a1f2, a1f3, a1f4, a1f5, a1f6, a1f7;
        GEMM0_STEP(0) GEMM0_STEP(1) GEMM0_STEP(2) GEMM0_STEP(3)
        GEMM0_STEP(4) GEMM0_STEP(5) GEMM0_STEP(6) GEMM0_STEP(7)

        // ---- GEMM1: H2pre^T = W2'^T @ H1^T (+bias row); tanh -> h2/a2 frags
        half4 h2f0, h2f1, h2f2, h2f3, h2f4, h2f5, h2f6, h2f7;
        half4 a2f0, a2f1, a2f2, a2f3, a2f4, a2f5, a2f6, a2f7;
        GEMM1_NTP(0, h2f0, a2f0, h2f1, a2f1)
        GEMM1_NTP(1, h2f2, a2f2, h2f3, a2f3)
        GEMM1_NTP(2, h2f4, a2f4, h2f5, a2f5)
        GEMM1_NTP(3, h2f6, a2f6, h2f7, a2f7)

        // ---- GEMM3: dz^T = W3^T @ H2^T (+bias row); rows = output dim d
        floatx4 acc3 = {0.f, 0.f, 0.f, 0.f};
        G3(0, h2f0) G3(1, h2f1) G3(2, h2f2) G3(3, h2f3)
        FENCE();
        G3(4, h2f4) G3(5, h2f5) G3(6, h2f6) G3(7, h2f7) G3(8, e1)
        if (q < 2) {   // d = q*4+r in [0,8): one float4 store per lane
            float4 o; o.x = acc3[0]; o.y = acc3[1]; o.z = acc3[2]; o.w = acc3[3];
            *(float4*)(out + (size_t)(s0 + p) * 8 + q * 4) = o;
        }
        FENCE();

        // ---- GEMM2: U^T = G @ A2^T, folded into trace immediately
        float tr = 0.0f;
        GEMM2_NTP(0, a1f0, a1f1)
        GEMM2_NTP(1, a1f2, a1f3)
        GEMM2_NTP(2, a1f4, a1f5)
        GEMM2_NTP(3, a1f6, a1f7)

        // ---- trace reduce across quads (rows of U^T), write -trace
        tr += __shfl_xor(tr, 16, 64);
        tr += __shfl_xor(tr, 32, 64);
        if (q == 0) out[(size_t)BATCH * 8 + s0 + p] = -tr;
        FENCE();
    }
}

extern "C" void kernel_launch(void* const* d_in, const int* in_sizes, int n_in,
                              void* d_out, int out_size, void* d_ws, size_t ws_size,
                              hipStream_t stream) {
    const float* z  = (const float*)d_in[0];
    // d_in[1] = logp_z (unused by the reference math)
    const float* t  = (const float*)d_in[2];
    const float* W1 = (const float*)d_in[3];
    const float* b1 = (const float*)d_in[4];
    const float* W2 = (const float*)d_in[5];
    const float* b2 = (const float*)d_in[6];
    const float* W3 = (const float*)d_in[7];
    const float* b3 = (const float*)d_in[8];
    _Float16* ws = (_Float16*)d_ws;
    float* out = (float*)d_out;

    prep_kernel<<<153, 256, 0, stream>>>(W1, b1, W2, b2, W3, b3, ws);
    cnf_main<<<1024, 256, 0, stream>>>(z, t, ws, out);
}